// Round 14
// baseline (145.166 us; speedup 1.0000x reference)
//
#include <hip/hip_runtime.h>

typedef __attribute__((ext_vector_type(8))) short short8;
typedef __attribute__((ext_vector_type(8))) unsigned short ushort8;
typedef __attribute__((ext_vector_type(4))) unsigned short ushort4v;
typedef __attribute__((ext_vector_type(4))) int int4v;
typedef __attribute__((ext_vector_type(4))) float f32x4;

#define Mdim 64
#define Kdim 8192
#define Ndim 8192
#define GRP 128
#define NGRP 64
#define KSPLIT 8
#define NG2 (NGRP / KSPLIT)   // 8 groups per block
#define BN 128

// Swizzled element offset in a [row][128]-bf16 LDS tile (256 B rows).
#define SWZ(row, kk) ((row)*128 + ((kk) ^ (8*((((row) >> 3) ^ (row)) & 7))))

__device__ __forceinline__ unsigned short f2bf(float f) {
    unsigned int u = __builtin_bit_cast(unsigned int, f);
    u += 0x7FFFu + ((u >> 16) & 1u);   // round-to-nearest-even
    return (unsigned short)(u >> 16);
}
__device__ __forceinline__ float bf2f(unsigned short h) {
    unsigned int u = ((unsigned int)h) << 16;
    return __builtin_bit_cast(float, u);
}

// blocks 0..511: build xh/xl (hi/lo bf16 split) + xsum[g][m].
// blocks 512..1023: out = bias (qlin atomically accumulates into it).
__global__ void prep_init_kernel(const float* __restrict__ x,
                                 unsigned short* __restrict__ xh,
                                 unsigned short* __restrict__ xl,
                                 float* __restrict__ xsum,
                                 const float* __restrict__ bias,
                                 float* __restrict__ out) {
    const int tid = threadIdx.x;
    if (blockIdx.x >= 512) {
        const size_t e = ((size_t)(blockIdx.x - 512) * 256 + tid) * 4;
        const int n = (int)(e & (Ndim - 1));
        *(f32x4*)(out + e) = *(const f32x4*)(bias + n);
        return;
    }
    const int u = blockIdx.x * 8 + (tid >> 5);
    const int g = u & (NGRP - 1);
    const int m = u >> 6;
    const int lane = tid & 31;
    const int k = g * GRP + lane * 4;
    f32x4 v = *(const f32x4*)(x + (size_t)m * Kdim + k);
    ushort4v hv, lv;
    float s = 0.f;
#pragma unroll
    for (int i = 0; i < 4; ++i) {
        unsigned short h = f2bf(v[i]);
        hv[i] = h;
        lv[i] = f2bf(v[i] - bf2f(h));
        s += v[i];
    }
    *(ushort4v*)(xh + (size_t)m * Kdim + k) = hv;
    *(ushort4v*)(xl + (size_t)m * Kdim + k) = lv;
#pragma unroll
    for (int off = 16; off > 0; off >>= 1) s += __shfl_down(s, off, 32);
    if (lane == 0) xsum[g * Mdim + m] = s;
}

// Main: 512 blocks = 64 n-tiles (BN=128) x KSPLIT=8 -> 2 blocks/CU (64 KB
// LDS, VGPR<=128). Sibling pairs (bid, bid+256) share kh -> same k-rows
// (DRAM-coherent); one block's WRITEQ drain is covered by its sibling.
// 512 threads = 8 waves = 2 m-tiles(32) x 4 n-strips(32).
// Counted-vmcnt + RAW barriers (R11): per slot: compute(g) -> s_barrier
// (readers done; q/x single-buffered) -> WRITEX [waits x(g+1)] -> szx_c=_n
// -> LOAD_SZX/X(g+2) -> WRITEQ [waits q(g+1); x(g+2) in flight] ->
// LOADQ(g+2) -> lgkmcnt(0)+s_barrier.
__launch_bounds__(512, 4)
__global__ void qlin_kernel(const unsigned short* __restrict__ xh,
                            const unsigned short* __restrict__ xl,
                            const int* __restrict__ qw,
                            const float* __restrict__ scales,
                            const float* __restrict__ zeros,
                            const float* __restrict__ xsum,
                            float* __restrict__ out) {
    __shared__ unsigned short lq[128 * 128];    // 32 KB [SWZ(n,k)] single-buf
    __shared__ unsigned short lxh[64 * 128];    // 16 KB single-buf
    __shared__ unsigned short lxl[64 * 128];    // 16 KB single-buf

    const int tid = threadIdx.x;
    const int kh = blockIdx.x & (KSPLIT - 1);
    const int n0 = (blockIdx.x >> 3) * BN;
    const int g0 = kh * NG2;

    const int w = tid >> 6;
    const int l = tid & 63;
    const int lcol = l & 15;
    const int lhi = l >> 4;
    const int mt = (w >> 2) * 32;     // m-tile base: 0 or 32
    const int ns = (w & 3) * 32;      // n-strip base: 0,32,64,96

    const int qc = tid & 31;          // q staging: 16B col-chunk
    const int qr = tid >> 5;          // q staging: row octet
    const int xc = tid & 15;          // x staging: 8-elem chunk
    const int xm = tid >> 4;          // x staging: row

    const int c0 = n0 + ns + lcol;
    const int c1 = c0 + 16;

    int4v qv[8];
    ushort8 xga, xgb, xgc, xgd;
    float sn0, sn1, zn0, zn1, sc0, sc1, zc0, zc1;
    f32x4 xsn0, xsn1, xsc0, xsc1;

    auto LOAD_SZX = [&](int g) {      // issue FIRST (oldest in vmcnt queue)
        sn0 = scales[(size_t)g * Ndim + c0];
        sn1 = scales[(size_t)g * Ndim + c1];
        zn0 = zeros[(size_t)g * Ndim + c0];
        zn1 = zeros[(size_t)g * Ndim + c1];
        xsn0 = *(const f32x4*)(xsum + g * Mdim + mt + lhi * 4);
        xsn1 = *(const f32x4*)(xsum + g * Mdim + mt + 16 + lhi * 4);
    };
    auto LOADX = [&](int g) {
        const size_t kb = (size_t)g * GRP + xc * 8;
        xga = *(const ushort8*)(xh + (size_t)xm * Kdim + kb);
        xgb = *(const ushort8*)(xh + (size_t)(xm + 32) * Kdim + kb);
        xgc = *(const ushort8*)(xl + (size_t)xm * Kdim + kb);
        xgd = *(const ushort8*)(xl + (size_t)(xm + 32) * Kdim + kb);
    };
    auto LOADQ = [&](int g) {         // youngest in queue
        const size_t kb = (size_t)g * GRP + qr * 8;
        const int nc = n0 + qc * 4;
#pragma unroll
        for (int j = 0; j < 8; ++j)
            qv[j] = *(const int4v*)(qw + (kb + j) * Ndim + nc);
    };
    auto WRITEX = [&]() {
        *(ushort8*)&lxh[SWZ(xm, xc * 8)] = xga;
        *(ushort8*)&lxh[SWZ(xm + 32, xc * 8)] = xgb;
        *(ushort8*)&lxl[SWZ(xm, xc * 8)] = xgc;
        *(ushort8*)&lxl[SWZ(xm + 32, xc * 8)] = xgd;
    };
    auto WRITEQ = [&]() {             // exact int->bf16 (|q|<=128 => truncation exact)
#pragma unroll
        for (int i = 0; i < 4; ++i) {
            int4v pk;
#pragma unroll
            for (int t = 0; t < 4; ++t) {
                unsigned lo = __builtin_bit_cast(unsigned, (float)qv[2 * t][i]) >> 16;
                unsigned hi = __builtin_bit_cast(unsigned, (float)qv[2 * t + 1][i]) & 0xFFFF0000u;
                pk[t] = (int)(lo | hi);
            }
            *(int4v*)&lq[SWZ(qc * 4 + i, qr * 8)] = pk;
        }
    };
    auto CCOPY = [&]() {
        sc0 = sn0; sc1 = sn1; zc0 = zn0; zc1 = zn1; xsc0 = xsn0; xsc1 = xsn1;
    };

    f32x4 acc00 = {0,0,0,0}, acc01 = {0,0,0,0}, acc10 = {0,0,0,0}, acc11 = {0,0,0,0};

    // ---- prologue: stage g0 (one full drain); szx/x/q(g0+1) left in flight
    LOAD_SZX(g0);
    LOADX(g0);
    LOADQ(g0);
    WRITEX();
    WRITEQ();
    CCOPY();
    LOAD_SZX(g0 + 1);
    LOADX(g0 + 1);
    LOADQ(g0 + 1);
    asm volatile("s_waitcnt lgkmcnt(0)" ::: "memory");
    __builtin_amdgcn_s_barrier();

    for (int g = 0; g < NG2; ++g) {
        // compute phase: lgkm-only; szx/x/q(g+1) arriving underneath
        f32x4 p00 = {0,0,0,0}, p01 = {0,0,0,0}, p10 = {0,0,0,0}, p11 = {0,0,0,0};
#pragma unroll
        for (int ks = 0; ks < 4; ++ks) {
            const int kk = ks * 32 + lhi * 8;
            short8 bq0 = *(const short8*)&lq[SWZ(ns + lcol, kk)];
            short8 bq1 = *(const short8*)&lq[SWZ(ns + 16 + lcol, kk)];
            short8 ah0 = *(const short8*)&lxh[SWZ(mt + lcol, kk)];
            short8 al0 = *(const short8*)&lxl[SWZ(mt + lcol, kk)];
            short8 ah1 = *(const short8*)&lxh[SWZ(mt + 16 + lcol, kk)];
            short8 al1 = *(const short8*)&lxl[SWZ(mt + 16 + lcol, kk)];
            p00 = __builtin_amdgcn_mfma_f32_16x16x32_bf16(ah0, bq0, p00, 0, 0, 0);
            p00 = __builtin_amdgcn_mfma_f32_16x16x32_bf16(al0, bq0, p00, 0, 0, 0);
            p01 = __builtin_amdgcn_mfma_f32_16x16x32_bf16(ah0, bq1, p01, 0, 0, 0);
            p01 = __builtin_amdgcn_mfma_f32_16x16x32_bf16(al0, bq1, p01, 0, 0, 0);
            p10 = __builtin_amdgcn_mfma_f32_16x16x32_bf16(ah1, bq0, p10, 0, 0, 0);
            p10 = __builtin_amdgcn_mfma_f32_16x16x32_bf16(al1, bq0, p10, 0, 0, 0);
            p11 = __builtin_amdgcn_mfma_f32_16x16x32_bf16(ah1, bq1, p11, 0, 0, 0);
            p11 = __builtin_amdgcn_mfma_f32_16x16x32_bf16(al1, bq1, p11, 0, 0, 0);
        }
#pragma unroll
        for (int r = 0; r < 4; ++r) {
            acc00[r] += sc0 * (p00[r] - zc0 * xsc0[r]);
            acc01[r] += sc1 * (p01[r] - zc1 * xsc0[r]);
            acc10[r] += sc0 * (p10[r] - zc0 * xsc1[r]);
            acc11[r] += sc1 * (p11[r] - zc1 * xsc1[r]);
        }

        if (g + 1 < NG2) {
            __builtin_amdgcn_s_barrier();         // all readers done (single-buf)
            WRITEX();                             // waits x(g+1); q(g+1) stays
            CCOPY();                              // szx(g+1): older, already landed
            if (g + 2 < NG2) {
                LOAD_SZX(g0 + g + 2);
                LOADX(g0 + g + 2);                // outstanding during q drain
                __builtin_amdgcn_sched_barrier(0);
            }
            WRITEQ();                             // waits q(g+1); x(g+2) in flight
            if (g + 2 < NG2) {
                LOADQ(g0 + g + 2);                // refill queue immediately
                __builtin_amdgcn_sched_barrier(0);
            }
            asm volatile("s_waitcnt lgkmcnt(0)" ::: "memory");
            __builtin_amdgcn_s_barrier();         // RAW: vmcnt survives
        }
    }

    // epilogue: accumulate into bias-initialized out (fp32 atomics, L2-side)
#pragma unroll
    for (int r = 0; r < 4; ++r) {
        atomicAdd(out + (size_t)(mt + lhi * 4 + r) * Ndim + c0, acc00[r]);
        atomicAdd(out + (size_t)(mt + lhi * 4 + r) * Ndim + c1, acc01[r]);
        atomicAdd(out + (size_t)(mt + 16 + lhi * 4 + r) * Ndim + c0, acc10[r]);
        atomicAdd(out + (size_t)(mt + 16 + lhi * 4 + r) * Ndim + c1, acc11[r]);
    }
}

extern "C" void kernel_launch(void* const* d_in, const int* in_sizes, int n_in,
                              void* d_out, int out_size, void* d_ws, size_t ws_size,
                              hipStream_t stream) {
    const float* x = (const float*)d_in[0];
    const int* qw = (const int*)d_in[1];
    const float* scales = (const float*)d_in[2];
    const float* zeros = (const float*)d_in[3];
    const float* bias = (const float*)d_in[4];

    unsigned short* xh = (unsigned short*)d_ws;
    unsigned short* xl = xh + (size_t)Mdim * Kdim;
    float* xsum = (float*)(xl + (size_t)Mdim * Kdim);
    float* out = (float*)d_out;

    prep_init_kernel<<<1024, 256, 0, stream>>>(x, xh, xl, xsum, bias, out);
    qlin_kernel<<<(Ndim / BN) * KSPLIT, 512, 0, stream>>>(xh, xl, qw, scales, zeros, xsum, out);
}

// Round 15
// 140.059 us; speedup vs baseline: 1.0365x; 1.0365x over previous
//
#include <hip/hip_runtime.h>

typedef __attribute__((ext_vector_type(8))) short short8;
typedef __attribute__((ext_vector_type(8))) unsigned short ushort8;
typedef __attribute__((ext_vector_type(4))) unsigned short ushort4v;
typedef __attribute__((ext_vector_type(4))) int int4v;
typedef __attribute__((ext_vector_type(4))) float f32x4;

#define Mdim 64
#define Kdim 8192
#define Ndim 8192
#define GRP 128
#define NGRP 64
#define KSPLIT 4
#define NG2 (NGRP / KSPLIT)   // 16 groups per block
#define BN 128

// Swizzled element offset in a [row][128]-bf16 LDS tile (256 B rows).
#define SWZ(row, kk) ((row)*128 + ((kk) ^ (8*((((row) >> 3) ^ (row)) & 7))))

__device__ __forceinline__ unsigned short f2bf(float f) {
    unsigned int u = __builtin_bit_cast(unsigned int, f);
    u += 0x7FFFu + ((u >> 16) & 1u);   // round-to-nearest-even
    return (unsigned short)(u >> 16);
}
__device__ __forceinline__ float bf2f(unsigned short h) {
    unsigned int u = ((unsigned int)h) << 16;
    return __builtin_bit_cast(float, u);
}

// Build xh/xl (hi/lo bf16 split of x) and xsum[g][m]; block 0 zeros the
// per-n-tile completion counters (stream-ordered before qlin; replay-safe).
__global__ void prep_kernel(const float* __restrict__ x,
                            unsigned short* __restrict__ xh,
                            unsigned short* __restrict__ xl,
                            float* __restrict__ xsum,
                            int* __restrict__ cnt) {
    const int tid = threadIdx.x;
    if (blockIdx.x == 0 && tid < 64) cnt[tid] = 0;
    const int u = blockIdx.x * 8 + (tid >> 5);
    const int g = u & (NGRP - 1);
    const int m = u >> 6;
    const int lane = tid & 31;
    const int k = g * GRP + lane * 4;
    f32x4 v = *(const f32x4*)(x + (size_t)m * Kdim + k);
    ushort4v hv, lv;
    float s = 0.f;
#pragma unroll
    for (int i = 0; i < 4; ++i) {
        unsigned short h = f2bf(v[i]);
        hv[i] = h;
        lv[i] = f2bf(v[i] - bf2f(h));
        s += v[i];
    }
    *(ushort4v*)(xh + (size_t)m * Kdim + k) = hv;
    *(ushort4v*)(xl + (size_t)m * Kdim + k) = lv;
#pragma unroll
    for (int off = 16; off > 0; off >>= 1) s += __shfl_down(s, off, 32);
    if (lane == 0) xsum[g * Mdim + m] = s;
}

// Main: 256 blocks = 64 n-tiles (BN=128) x KSPLIT=4, 1 block/CU (148 KB LDS).
// Exact R11 k-loop (proven 56.2us): double-buffered q+x LDS, LDS epilogue
// tables, counted-vmcnt, RAW barriers. Fused tail: each block stores partials
// to pout, fence+counter; LAST kh-block per n-tile sums 4 partials + bias in
// fixed order (deterministic) and writes out. No standalone reduce pass.
__launch_bounds__(512, 2)
__global__ void qlin_kernel(const unsigned short* __restrict__ xh,
                            const unsigned short* __restrict__ xl,
                            const int* __restrict__ qw,
                            const float* __restrict__ scales,
                            const float* __restrict__ zeros,
                            const float* __restrict__ xsum,
                            float* __restrict__ pout,
                            int* __restrict__ cnt,
                            const float* __restrict__ bias,
                            float* __restrict__ out) {
    __shared__ unsigned short lq[2][128 * 128];   // 2x32 KB [SWZ(n,k)]
    __shared__ unsigned short lxh[2][64 * 128];   // 2x16 KB
    __shared__ unsigned short lxl[2][64 * 128];   // 2x16 KB
    __shared__ float ls[NG2][128];                // 8 KB scales slice
    __shared__ float lz[NG2][128];                // 8 KB zeros slice
    __shared__ float lxs[NG2][64];                // 4 KB xsum slice
    __shared__ int lflag;

    const int tid = threadIdx.x;
    const int kh = blockIdx.x & (KSPLIT - 1);
    const int nt = blockIdx.x >> 2;
    const int n0 = nt * BN;
    const int g0 = kh * NG2;

    const int w = tid >> 6;
    const int l = tid & 63;
    const int lcol = l & 15;
    const int lhi = l >> 4;
    const int mt = (w >> 2) * 32;     // m-tile base: 0 or 32
    const int ns = (w & 3) * 32;      // n-strip base: 0,32,64,96

    const int qc = tid & 31;          // q staging: 16B col-chunk
    const int qr = tid >> 5;          // q staging: row octet
    const int xc = tid & 15;          // x staging: 8-elem chunk
    const int xm = tid >> 4;          // x staging: row

    const int c0 = n0 + ns + lcol;
    const int c1 = c0 + 16;

    int4v qv[8];
    ushort8 xga, xgb, xgc, xgd;

    auto LOADX = [&](int g) {
        const size_t kb = (size_t)g * GRP + xc * 8;
        xga = *(const ushort8*)(xh + (size_t)xm * Kdim + kb);
        xgb = *(const ushort8*)(xh + (size_t)(xm + 32) * Kdim + kb);
        xgc = *(const ushort8*)(xl + (size_t)xm * Kdim + kb);
        xgd = *(const ushort8*)(xl + (size_t)(xm + 32) * Kdim + kb);
    };
    auto LOADQ = [&](int g) {
        const size_t kb = (size_t)g * GRP + qr * 8;
        const int nc = n0 + qc * 4;
#pragma unroll
        for (int j = 0; j < 8; ++j)
            qv[j] = *(const int4v*)(qw + (kb + j) * Ndim + nc);
    };
    auto WRITEX = [&](int b) {
        *(ushort8*)&lxh[b][SWZ(xm, xc * 8)] = xga;
        *(ushort8*)&lxh[b][SWZ(xm + 32, xc * 8)] = xgb;
        *(ushort8*)&lxl[b][SWZ(xm, xc * 8)] = xgc;
        *(ushort8*)&lxl[b][SWZ(xm + 32, xc * 8)] = xgd;
    };
    auto WRITEQ = [&](int b) {        // exact int->bf16 (|q|<=128 => truncation exact)
#pragma unroll
        for (int i = 0; i < 4; ++i) {
            int4v pk;
#pragma unroll
            for (int t = 0; t < 4; ++t) {
                unsigned lo = __builtin_bit_cast(unsigned, (float)qv[2 * t][i]) >> 16;
                unsigned hi = __builtin_bit_cast(unsigned, (float)qv[2 * t + 1][i]) & 0xFFFF0000u;
                pk[t] = (int)(lo | hi);
            }
            *(int4v*)&lq[b][SWZ(qc * 4 + i, qr * 8)] = pk;
        }
    };

    f32x4 acc00 = {0,0,0,0}, acc01 = {0,0,0,0}, acc10 = {0,0,0,0}, acc11 = {0,0,0,0};

    // ---- prologue: tables + group g0 staged; q/x(g0+1) left IN FLIGHT ----
    {
        const int tg = tid >> 5, tc = tid & 31;
        f32x4 sv = *(const f32x4*)(scales + (size_t)(g0 + tg) * Ndim + n0 + tc * 4);
        f32x4 zv = *(const f32x4*)(zeros + (size_t)(g0 + tg) * Ndim + n0 + tc * 4);
        float x0 = xsum[(g0 + (tid >> 6)) * Mdim + (tid & 63)];
        float x1 = xsum[(g0 + ((tid + 512) >> 6)) * Mdim + (tid & 63)];
        LOADX(g0);
        LOADQ(g0);
        *(f32x4*)&ls[tg][tc * 4] = sv;
        *(f32x4*)&lz[tg][tc * 4] = zv;
        (&lxs[0][0])[tid] = x0;
        (&lxs[0][0])[tid + 512] = x1;
        WRITEX(0);
        WRITEQ(0);                    // drains q(g0)
        LOADX(g0 + 1);
        LOADQ(g0 + 1);
        asm volatile("s_waitcnt lgkmcnt(0)" ::: "memory");
        __builtin_amdgcn_s_barrier();
    }

    for (int g = 0; g < NG2; ++g) {
        const int b = g & 1;

        // compute phase: lgkm-only; x/q(g+1) arriving underneath
        f32x4 p00 = {0,0,0,0}, p01 = {0,0,0,0}, p10 = {0,0,0,0}, p11 = {0,0,0,0};
#pragma unroll
        for (int ks = 0; ks < 4; ++ks) {
            const int kk = ks * 32 + lhi * 8;
            short8 bq0 = *(const short8*)&lq[b][SWZ(ns + lcol, kk)];
            short8 bq1 = *(const short8*)&lq[b][SWZ(ns + 16 + lcol, kk)];
            short8 ah0 = *(const short8*)&lxh[b][SWZ(mt + lcol, kk)];
            short8 al0 = *(const short8*)&lxl[b][SWZ(mt + lcol, kk)];
            short8 ah1 = *(const short8*)&lxh[b][SWZ(mt + 16 + lcol, kk)];
            short8 al1 = *(const short8*)&lxl[b][SWZ(mt + 16 + lcol, kk)];
            p00 = __builtin_amdgcn_mfma_f32_16x16x32_bf16(ah0, bq0, p00, 0, 0, 0);
            p00 = __builtin_amdgcn_mfma_f32_16x16x32_bf16(al0, bq0, p00, 0, 0, 0);
            p01 = __builtin_amdgcn_mfma_f32_16x16x32_bf16(ah0, bq1, p01, 0, 0, 0);
            p01 = __builtin_amdgcn_mfma_f32_16x16x32_bf16(al0, bq1, p01, 0, 0, 0);
            p10 = __builtin_amdgcn_mfma_f32_16x16x32_bf16(ah1, bq0, p10, 0, 0, 0);
            p10 = __builtin_amdgcn_mfma_f32_16x16x32_bf16(al1, bq0, p10, 0, 0, 0);
            p11 = __builtin_amdgcn_mfma_f32_16x16x32_bf16(ah1, bq1, p11, 0, 0, 0);
            p11 = __builtin_amdgcn_mfma_f32_16x16x32_bf16(al1, bq1, p11, 0, 0, 0);
        }
        {   // group fold (LDS tables only)
            const float s0 = ls[g][ns + lcol],      z0 = lz[g][ns + lcol];
            const float s1 = ls[g][ns + 16 + lcol], z1 = lz[g][ns + 16 + lcol];
            f32x4 xs0 = *(const f32x4*)&lxs[g][mt + lhi * 4];
            f32x4 xs1 = *(const f32x4*)&lxs[g][mt + 16 + lhi * 4];
#pragma unroll
            for (int r = 0; r < 4; ++r) {
                acc00[r] += s0 * (p00[r] - z0 * xs0[r]);
                acc01[r] += s1 * (p01[r] - z1 * xs0[r]);
                acc10[r] += s0 * (p10[r] - z0 * xs1[r]);
                acc11[r] += s1 * (p11[r] - z1 * xs1[r]);
            }
        }

        if (g + 1 < NG2) {
            WRITEX(b ^ 1);                        // waits x(g+1); q(g+1) stays
            if (g + 2 < NG2) {
                LOADX(g0 + g + 2);                // outstanding during q drain
                __builtin_amdgcn_sched_barrier(0);
            }
            WRITEQ(b ^ 1);                        // waits q(g+1); x(g+2) in flight
            if (g + 2 < NG2) {
                LOADQ(g0 + g + 2);                // refill queue immediately
                __builtin_amdgcn_sched_barrier(0);
            }
            asm volatile("s_waitcnt lgkmcnt(0)" ::: "memory");
            __builtin_amdgcn_s_barrier();         // RAW: vmcnt survives
        }
    }

    // ---- store partials (plain stores; no cross-XCD atomics on out) ----
    const size_t ob = (size_t)kh * Mdim * Ndim;
#pragma unroll
    for (int r = 0; r < 4; ++r) {
        pout[ob + (size_t)(mt + lhi * 4 + r) * Ndim + c0] = acc00[r];
        pout[ob + (size_t)(mt + lhi * 4 + r) * Ndim + c1] = acc01[r];
        pout[ob + (size_t)(mt + 16 + lhi * 4 + r) * Ndim + c0] = acc10[r];
        pout[ob + (size_t)(mt + 16 + lhi * 4 + r) * Ndim + c1] = acc11[r];
    }

    // ---- completion counter; last kh-block for this n-tile does the sum ----
    __threadfence();                              // release partials (device scope)
    __syncthreads();
    if (tid == 0) lflag = atomicAdd(&cnt[nt], 1);
    __syncthreads();
    if (lflag == KSPLIT - 1) {
        __threadfence();                          // acquire others' partials
        // n-tile = 64 rows x 128 cols = 2048 float4; 512 threads x 4 each
#pragma unroll
        for (int j = 0; j < 4; ++j) {
            const int i = tid * 4 + j;            // float4 index in tile
            const int m = i >> 5;
            const int c4 = (i & 31) * 4;
            const size_t e = (size_t)m * Ndim + n0 + c4;
            f32x4 a = *(const f32x4*)(bias + n0 + c4);
#pragma unroll
            for (int s = 0; s < KSPLIT; ++s) {    // fixed order -> deterministic
                f32x4 pp = *(const f32x4*)(pout + (size_t)s * Mdim * Ndim + e);
#pragma unroll
                for (int r = 0; r < 4; ++r) a[r] += pp[r];
            }
            *(f32x4*)(out + e) = a;
        }
    }
}

extern "C" void kernel_launch(void* const* d_in, const int* in_sizes, int n_in,
                              void* d_out, int out_size, void* d_ws, size_t ws_size,
                              hipStream_t stream) {
    const float* x = (const float*)d_in[0];
    const int* qw = (const int*)d_in[1];
    const float* scales = (const float*)d_in[2];
    const float* zeros = (const float*)d_in[3];
    const float* bias = (const float*)d_in[4];

    unsigned short* xh = (unsigned short*)d_ws;
    unsigned short* xl = xh + (size_t)Mdim * Kdim;
    float* xsum = (float*)(xl + (size_t)Mdim * Kdim);
    float* pout = xsum + NGRP * Mdim;
    int* cnt = (int*)(pout + (size_t)KSPLIT * Mdim * Ndim);
    float* out = (float*)d_out;

    prep_kernel<<<512, 256, 0, stream>>>(x, xh, xl, xsum, cnt);
    qlin_kernel<<<(Ndim / BN) * KSPLIT, 512, 0, stream>>>(xh, xl, qw, scales, zeros,
                                                          xsum, pout, cnt, bias, out);
}

// Round 16
// 56.814 us; speedup vs baseline: 2.5551x; 2.4652x over previous
//
#include <hip/hip_runtime.h>

typedef __attribute__((ext_vector_type(8))) short short8;
typedef __attribute__((ext_vector_type(8))) unsigned short ushort8;
typedef __attribute__((ext_vector_type(4))) unsigned short ushort4v;
typedef __attribute__((ext_vector_type(4))) int int4v;
typedef __attribute__((ext_vector_type(2))) int int2v;
typedef __attribute__((ext_vector_type(4))) float f32x4;

#define Mdim 64
#define Kdim 8192
#define Ndim 8192
#define GRP 128
#define NGRP 64
#define KSPLIT 4
#define NG2 (NGRP / KSPLIT)   // 16 groups per block
#define BN 128

// Swizzled element offset in a [row][128]-bf16 LDS tile (256 B rows).
#define SWZ(row, kk) ((row)*128 + ((kk) ^ (8*((((row) >> 3) ^ (row)) & 7))))

__device__ __forceinline__ unsigned short f2bf(float f) {
    unsigned int u = __builtin_bit_cast(unsigned int, f);
    u += 0x7FFFu + ((u >> 16) & 1u);   // round-to-nearest-even
    return (unsigned short)(u >> 16);
}
__device__ __forceinline__ float bf2f(unsigned short h) {
    unsigned int u = ((unsigned int)h) << 16;
    return __builtin_bit_cast(float, u);
}

// Build xh/xl (hi/lo bf16 split of x) and per-(group,m) sums xsum[g][m].
__global__ void prep_kernel(const float* __restrict__ x,
                            unsigned short* __restrict__ xh,
                            unsigned short* __restrict__ xl,
                            float* __restrict__ xsum) {
    const int tid = threadIdx.x;
    const int u = blockIdx.x * 8 + (tid >> 5);
    const int g = u & (NGRP - 1);
    const int m = u >> 6;
    const int lane = tid & 31;
    const int k = g * GRP + lane * 4;
    f32x4 v = *(const f32x4*)(x + (size_t)m * Kdim + k);
    ushort4v hv, lv;
    float s = 0.f;
#pragma unroll
    for (int i = 0; i < 4; ++i) {
        unsigned short h = f2bf(v[i]);
        hv[i] = h;
        lv[i] = f2bf(v[i] - bf2f(h));
        s += v[i];
    }
    *(ushort4v*)(xh + (size_t)m * Kdim + k) = hv;
    *(ushort4v*)(xl + (size_t)m * Kdim + k) = lv;
#pragma unroll
    for (int off = 16; off > 0; off >>= 1) s += __shfl_down(s, off, 32);
    if (lane == 0) xsum[g * Mdim + m] = s;
}

// Half-set q load: 4 rows x 16B per thread into a NAMED reg set.
#define LOADQ_H(dst, g, j0) do {                                              \
    const size_t kb_ = (size_t)(g) * GRP + qr * 8 + (j0);                     \
    const int nc_ = n0 + qc * 4;                                              \
    _Pragma("unroll")                                                         \
    for (int j = 0; j < 4; ++j)                                               \
        dst[j] = *(const int4v*)(qw + (kb_ + j) * Ndim + nc_);                \
} while (0)

// Half-set staging: exact int->bf16 (|q|<=128 => truncation exact),
// ds_write_b64 at element offset SWZ(row, 8qr)+(j0). (+4 elems survives the
// XOR since the swizzle only flips bits >=3 of kk.)
#define WRITEQ_H(src, b, j0) do {                                             \
    _Pragma("unroll")                                                         \
    for (int i = 0; i < 4; ++i) {                                             \
        int2v pk_;                                                            \
        _Pragma("unroll")                                                     \
        for (int t = 0; t < 2; ++t) {                                         \
            unsigned lo_ = __builtin_bit_cast(unsigned, (float)src[2*t][i]) >> 16;           \
            unsigned hi_ = __builtin_bit_cast(unsigned, (float)src[2*t+1][i]) & 0xFFFF0000u; \
            pk_[t] = (int)(lo_ | hi_);                                        \
        }                                                                     \
        *(int2v*)&lq[b][SWZ(qc * 4 + i, qr * 8) + (j0)] = pk_;                \
    }                                                                         \
} while (0)

// Main: 256 blocks = 64 n-tiles (BN=128) x KSPLIT=4, 1 block/CU (148 KB LDS).
// R11's proven structure (double-buffered q+x LDS, LDS epilogue tables,
// counted-vmcnt, RAW barriers) + split q staging (A/B half-sets): WRITEQ_A
// waits only qA(g+1) (qB still in flight), LOADQ_A(g+2) reissues immediately,
// then WRITEQ_B / LOADQ_B -> the per-CU HBM queue never runs dry.
__launch_bounds__(512, 2)
__global__ void qlin_kernel(const unsigned short* __restrict__ xh,
                            const unsigned short* __restrict__ xl,
                            const int* __restrict__ qw,
                            const float* __restrict__ scales,
                            const float* __restrict__ zeros,
                            const float* __restrict__ xsum,
                            float* __restrict__ pout) {
    __shared__ unsigned short lq[2][128 * 128];   // 2x32 KB [SWZ(n,k)]
    __shared__ unsigned short lxh[2][64 * 128];   // 2x16 KB
    __shared__ unsigned short lxl[2][64 * 128];   // 2x16 KB
    __shared__ float ls[NG2][128];                // 8 KB scales slice
    __shared__ float lz[NG2][128];                // 8 KB zeros slice
    __shared__ float lxs[NG2][64];                // 4 KB xsum slice

    const int tid = threadIdx.x;
    const int kh = blockIdx.x & (KSPLIT - 1);
    const int n0 = (blockIdx.x >> 2) * BN;
    const int g0 = kh * NG2;

    const int w = tid >> 6;
    const int l = tid & 63;
    const int lcol = l & 15;
    const int lhi = l >> 4;
    const int mt = (w >> 2) * 32;     // m-tile base: 0 or 32
    const int ns = (w & 3) * 32;      // n-strip base: 0,32,64,96

    const int qc = tid & 31;          // q staging: 16B col-chunk
    const int qr = tid >> 5;          // q staging: row octet
    const int xc = tid & 15;          // x staging: 8-elem chunk
    const int xm = tid >> 4;          // x staging: row

    const int c0 = n0 + ns + lcol;
    const int c1 = c0 + 16;

    int4v qva[4], qvb[4];             // two half-sets (same 32 VGPR as before)
    ushort8 xga, xgb, xgc, xgd;

    auto LOADX = [&](int g) {
        const size_t kb = (size_t)g * GRP + xc * 8;
        xga = *(const ushort8*)(xh + (size_t)xm * Kdim + kb);
        xgb = *(const ushort8*)(xh + (size_t)(xm + 32) * Kdim + kb);
        xgc = *(const ushort8*)(xl + (size_t)xm * Kdim + kb);
        xgd = *(const ushort8*)(xl + (size_t)(xm + 32) * Kdim + kb);
    };
    auto WRITEX = [&](int b) {
        *(ushort8*)&lxh[b][SWZ(xm, xc * 8)] = xga;
        *(ushort8*)&lxh[b][SWZ(xm + 32, xc * 8)] = xgb;
        *(ushort8*)&lxl[b][SWZ(xm, xc * 8)] = xgc;
        *(ushort8*)&lxl[b][SWZ(xm + 32, xc * 8)] = xgd;
    };

    f32x4 acc00 = {0,0,0,0}, acc01 = {0,0,0,0}, acc10 = {0,0,0,0}, acc11 = {0,0,0,0};

    // ---- prologue: tables + group g0 staged; x/q(g0+1) left IN FLIGHT ----
    {
        const int tg = tid >> 5, tc = tid & 31;
        f32x4 sv = *(const f32x4*)(scales + (size_t)(g0 + tg) * Ndim + n0 + tc * 4);
        f32x4 zv = *(const f32x4*)(zeros + (size_t)(g0 + tg) * Ndim + n0 + tc * 4);
        float x0 = xsum[(g0 + (tid >> 6)) * Mdim + (tid & 63)];
        float x1 = xsum[(g0 + ((tid + 512) >> 6)) * Mdim + (tid & 63)];
        LOADX(g0);
        LOADQ_H(qva, g0, 0);
        LOADQ_H(qvb, g0, 4);
        *(f32x4*)&ls[tg][tc * 4] = sv;
        *(f32x4*)&lz[tg][tc * 4] = zv;
        (&lxs[0][0])[tid] = x0;
        (&lxs[0][0])[tid + 512] = x1;
        WRITEX(0);
        WRITEQ_H(qva, 0, 0);
        WRITEQ_H(qvb, 0, 4);          // drains q(g0)
        LOADX(g0 + 1);
        LOADQ_H(qva, g0 + 1, 0);
        LOADQ_H(qvb, g0 + 1, 4);
        asm volatile("s_waitcnt lgkmcnt(0)" ::: "memory");
        __builtin_amdgcn_s_barrier();
    }

    for (int g = 0; g < NG2; ++g) {
        const int b = g & 1;

        // compute phase: lgkm-only; x/q(g+1) arriving underneath
        f32x4 p00 = {0,0,0,0}, p01 = {0,0,0,0}, p10 = {0,0,0,0}, p11 = {0,0,0,0};
#pragma unroll
        for (int ks = 0; ks < 4; ++ks) {
            const int kk = ks * 32 + lhi * 8;
            short8 bq0 = *(const short8*)&lq[b][SWZ(ns + lcol, kk)];
            short8 bq1 = *(const short8*)&lq[b][SWZ(ns + 16 + lcol, kk)];
            short8 ah0 = *(const short8*)&lxh[b][SWZ(mt + lcol, kk)];
            short8 al0 = *(const short8*)&lxl[b][SWZ(mt + lcol, kk)];
            short8 ah1 = *(const short8*)&lxh[b][SWZ(mt + 16 + lcol, kk)];
            short8 al1 = *(const short8*)&lxl[b][SWZ(mt + 16 + lcol, kk)];
            p00 = __builtin_amdgcn_mfma_f32_16x16x32_bf16(ah0, bq0, p00, 0, 0, 0);
            p00 = __builtin_amdgcn_mfma_f32_16x16x32_bf16(al0, bq0, p00, 0, 0, 0);
            p01 = __builtin_amdgcn_mfma_f32_16x16x32_bf16(ah0, bq1, p01, 0, 0, 0);
            p01 = __builtin_amdgcn_mfma_f32_16x16x32_bf16(al0, bq1, p01, 0, 0, 0);
            p10 = __builtin_amdgcn_mfma_f32_16x16x32_bf16(ah1, bq0, p10, 0, 0, 0);
            p10 = __builtin_amdgcn_mfma_f32_16x16x32_bf16(al1, bq0, p10, 0, 0, 0);
            p11 = __builtin_amdgcn_mfma_f32_16x16x32_bf16(ah1, bq1, p11, 0, 0, 0);
            p11 = __builtin_amdgcn_mfma_f32_16x16x32_bf16(al1, bq1, p11, 0, 0, 0);
        }
        {   // group fold (LDS tables only)
            const float s0 = ls[g][ns + lcol],      z0 = lz[g][ns + lcol];
            const float s1 = ls[g][ns + 16 + lcol], z1 = lz[g][ns + 16 + lcol];
            f32x4 xs0 = *(const f32x4*)&lxs[g][mt + lhi * 4];
            f32x4 xs1 = *(const f32x4*)&lxs[g][mt + 16 + lhi * 4];
#pragma unroll
            for (int r = 0; r < 4; ++r) {
                acc00[r] += s0 * (p00[r] - z0 * xs0[r]);
                acc01[r] += s1 * (p01[r] - z1 * xs0[r]);
                acc10[r] += s0 * (p10[r] - z0 * xs1[r]);
                acc11[r] += s1 * (p11[r] - z1 * xs1[r]);
            }
        }

        if (g + 1 < NG2) {
            WRITEX(b ^ 1);                        // waits x(g+1); q(g+1) stays
            if (g + 2 < NG2) {
                LOADX(g0 + g + 2);                // outstanding during q drain
                __builtin_amdgcn_sched_barrier(0);
            }
            WRITEQ_H(qva, b ^ 1, 0);              // waits qA(g+1); qB in flight
            if (g + 2 < NG2) {
                LOADQ_H(qva, g0 + g + 2, 0);      // refill A while B drains
                __builtin_amdgcn_sched_barrier(0);
            }
            WRITEQ_H(qvb, b ^ 1, 4);              // waits qB(g+1); A(g+2) in flight
            if (g + 2 < NG2) {
                LOADQ_H(qvb, g0 + g + 2, 4);      // refill B
                __builtin_amdgcn_sched_barrier(0);
            }
            asm volatile("s_waitcnt lgkmcnt(0)" ::: "memory");
            __builtin_amdgcn_s_barrier();         // RAW: vmcnt survives
        }
    }

    const size_t ob = (size_t)kh * Mdim * Ndim;
#pragma unroll
    for (int r = 0; r < 4; ++r) {
        pout[ob + (size_t)(mt + lhi * 4 + r) * Ndim + c0] = acc00[r];
        pout[ob + (size_t)(mt + lhi * 4 + r) * Ndim + c1] = acc01[r];
        pout[ob + (size_t)(mt + 16 + lhi * 4 + r) * Ndim + c0] = acc10[r];
        pout[ob + (size_t)(mt + 16 + lhi * 4 + r) * Ndim + c1] = acc11[r];
    }
}

// out = sum of KSPLIT partials + bias
__global__ void reduce_kernel(const float* __restrict__ pout,
                              const float* __restrict__ bias,
                              float* __restrict__ out) {
    const size_t e = ((size_t)blockIdx.x * 256 + threadIdx.x) * 4;
    const int n = (int)(e & (Ndim - 1));
    f32x4 a = *(const f32x4*)(bias + n);
#pragma unroll
    for (int s = 0; s < KSPLIT; ++s) {
        f32x4 ppart = *(const f32x4*)(pout + (size_t)s * Mdim * Ndim + e);
#pragma unroll
        for (int r = 0; r < 4; ++r) a[r] += ppart[r];
    }
    *(f32x4*)(out + e) = a;
}

extern "C" void kernel_launch(void* const* d_in, const int* in_sizes, int n_in,
                              void* d_out, int out_size, void* d_ws, size_t ws_size,
                              hipStream_t stream) {
    const float* x = (const float*)d_in[0];
    const int* qw = (const int*)d_in[1];
    const float* scales = (const float*)d_in[2];
    const float* zeros = (const float*)d_in[3];
    const float* bias = (const float*)d_in[4];

    unsigned short* xh = (unsigned short*)d_ws;
    unsigned short* xl = xh + (size_t)Mdim * Kdim;
    float* xsum = (float*)(xl + (size_t)Mdim * Kdim);
    float* pout = xsum + NGRP * Mdim;
    float* out = (float*)d_out;

    prep_kernel<<<512, 256, 0, stream>>>(x, xh, xl, xsum);
    qlin_kernel<<<(Ndim / BN) * KSPLIT, 512, 0, stream>>>(xh, xl, qw, scales, zeros, xsum, pout);
    reduce_kernel<<<(Mdim * Ndim / 4) / 256, 256, 0, stream>>>(pout, bias, out);
}

// Round 17
// 56.149 us; speedup vs baseline: 2.5854x; 1.0118x over previous
//
#include <hip/hip_runtime.h>

typedef __attribute__((ext_vector_type(8))) short short8;
typedef __attribute__((ext_vector_type(8))) unsigned short ushort8;
typedef __attribute__((ext_vector_type(4))) int int4v;
typedef __attribute__((ext_vector_type(4))) float f32x4;

#define Mdim 64
#define Kdim 8192
#define Ndim 8192
#define GRP 128
#define NGRP 64
#define KSPLIT 4
#define NG2 (NGRP / KSPLIT)   // 16 groups per block
#define BN 128

// Swizzled element offset in a [row][128]-bf16 LDS tile (256 B rows).
#define SWZ(row, kk) ((row)*128 + ((kk) ^ (8*((((row) >> 3) ^ (row)) & 7))))

__device__ __forceinline__ unsigned short f2bf(float f) {
    unsigned int u = __builtin_bit_cast(unsigned int, f);
    u += 0x7FFFu + ((u >> 16) & 1u);   // round-to-nearest-even
    return (unsigned short)(u >> 16);
}
__device__ __forceinline__ float bf2f(unsigned short h) {
    unsigned int u = ((unsigned int)h) << 16;
    return __builtin_bit_cast(float, u);
}

// Main: 256 blocks = 64 n-tiles (BN=128) x KSPLIT=4, 1 block/CU (144 KB LDS).
// R11's proven pipeline (double-buffered q+x LDS, LDS s/z tables, counted
// vmcnt, RAW barriers). NEW: no prep kernel —
//  - staging reads RAW fp32 x (same bytes as pre-split bf16 hi+lo) and does
//    the hi/lo split in WRITEX (VALU, hidden under the q stream);
//  - xsum computed in-kernel by ones-MFMA row-sum of the staged x tile
//    (numerically consistent: same bf16 values in q·x and z·sum(x) terms).
__launch_bounds__(512, 2)
__global__ void qlin_kernel(const float* __restrict__ x,
                            const int* __restrict__ qw,
                            const float* __restrict__ scales,
                            const float* __restrict__ zeros,
                            float* __restrict__ pout) {
    __shared__ unsigned short lq[2][128 * 128];   // 2x32 KB [SWZ(n,k)]
    __shared__ unsigned short lxh[2][64 * 128];   // 2x16 KB
    __shared__ unsigned short lxl[2][64 * 128];   // 2x16 KB
    __shared__ float ls[NG2][128];                // 8 KB scales slice
    __shared__ float lz[NG2][128];                // 8 KB zeros slice

    const int tid = threadIdx.x;
    const int kh = blockIdx.x & (KSPLIT - 1);
    const int n0 = (blockIdx.x >> 2) * BN;
    const int g0 = kh * NG2;

    const int w = tid >> 6;
    const int l = tid & 63;
    const int lcol = l & 15;
    const int lhi = l >> 4;
    const int mt = (w >> 2) * 32;     // m-tile base: 0 or 32
    const int ns = (w & 3) * 32;      // n-strip base: 0,32,64,96

    const int qc = tid & 31;          // q staging: 16B col-chunk
    const int qr = tid >> 5;          // q staging: row octet
    const int xc = tid & 15;          // x staging: 8-elem chunk
    const int xm = tid >> 4;          // x staging: row

    const int c0 = n0 + ns + lcol;
    const int c1 = c0 + 16;

    int4v qv[8];
    f32x4 xva, xvb, xvc, xvd;         // raw fp32 x: rows xm, xm+32 x 8 k each

    // all-ones bf16 B-fragment for the xsum row-sum MFMA
    short8 ones;
#pragma unroll
    for (int i = 0; i < 8; ++i) ones[i] = (short)0x3F80;

    auto LOADX = [&](int g) {         // 4x f32x4 = 64 B/thread (same as pre-split)
        const size_t kb = (size_t)g * GRP + xc * 8;
        xva = *(const f32x4*)(x + (size_t)xm * Kdim + kb);
        xvb = *(const f32x4*)(x + (size_t)xm * Kdim + kb + 4);
        xvc = *(const f32x4*)(x + (size_t)(xm + 32) * Kdim + kb);
        xvd = *(const f32x4*)(x + (size_t)(xm + 32) * Kdim + kb + 4);
    };
    auto LOADQ = [&](int g) {
        const size_t kb = (size_t)g * GRP + qr * 8;
        const int nc = n0 + qc * 4;
#pragma unroll
        for (int j = 0; j < 8; ++j)
            qv[j] = *(const int4v*)(qw + (kb + j) * Ndim + nc);
    };
    auto WRITEX = [&](int b) {        // hi/lo split at staging time
        ushort8 h0, l0, h1, l1;
#pragma unroll
        for (int i = 0; i < 4; ++i) {
            unsigned short h;
            h = f2bf(xva[i]); h0[i] = h;     l0[i] = f2bf(xva[i] - bf2f(h));
            h = f2bf(xvb[i]); h0[4 + i] = h; l0[4 + i] = f2bf(xvb[i] - bf2f(h));
            h = f2bf(xvc[i]); h1[i] = h;     l1[i] = f2bf(xvc[i] - bf2f(h));
            h = f2bf(xvd[i]); h1[4 + i] = h; l1[4 + i] = f2bf(xvd[i] - bf2f(h));
        }
        *(ushort8*)&lxh[b][SWZ(xm, xc * 8)] = h0;
        *(ushort8*)&lxl[b][SWZ(xm, xc * 8)] = l0;
        *(ushort8*)&lxh[b][SWZ(xm + 32, xc * 8)] = h1;
        *(ushort8*)&lxl[b][SWZ(xm + 32, xc * 8)] = l1;
    };
    auto WRITEQ = [&](int b) {        // exact int->bf16 (|q|<=128 => truncation exact)
#pragma unroll
        for (int i = 0; i < 4; ++i) {
            int4v pk;
#pragma unroll
            for (int t = 0; t < 4; ++t) {
                unsigned lo = __builtin_bit_cast(unsigned, (float)qv[2 * t][i]) >> 16;
                unsigned hi = __builtin_bit_cast(unsigned, (float)qv[2 * t + 1][i]) & 0xFFFF0000u;
                pk[t] = (int)(lo | hi);
            }
            *(int4v*)&lq[b][SWZ(qc * 4 + i, qr * 8)] = pk;
        }
    };

    f32x4 acc00 = {0,0,0,0}, acc01 = {0,0,0,0}, acc10 = {0,0,0,0}, acc11 = {0,0,0,0};

    // ---- prologue: s/z tables + group g0 staged; x/q(g0+1) left IN FLIGHT ----
    {
        const int tg = tid >> 5, tc = tid & 31;
        f32x4 sv = *(const f32x4*)(scales + (size_t)(g0 + tg) * Ndim + n0 + tc * 4);
        f32x4 zv = *(const f32x4*)(zeros + (size_t)(g0 + tg) * Ndim + n0 + tc * 4);
        LOADX(g0);
        LOADQ(g0);
        *(f32x4*)&ls[tg][tc * 4] = sv;
        *(f32x4*)&lz[tg][tc * 4] = zv;
        WRITEX(0);
        WRITEQ(0);                    // drains q(g0)
        LOADX(g0 + 1);
        LOADQ(g0 + 1);
        asm volatile("s_waitcnt lgkmcnt(0)" ::: "memory");
        __builtin_amdgcn_s_barrier();
    }

    for (int g = 0; g < NG2; ++g) {
        const int b = g & 1;

        // compute phase: lgkm-only; x/q(g+1) arriving underneath
        f32x4 p00 = {0,0,0,0}, p01 = {0,0,0,0}, p10 = {0,0,0,0}, p11 = {0,0,0,0};
        f32x4 ps0 = {0,0,0,0}, ps1 = {0,0,0,0};   // xsum row-sums via ones-MFMA
#pragma unroll
        for (int ks = 0; ks < 4; ++ks) {
            const int kk = ks * 32 + lhi * 8;
            short8 bq0 = *(const short8*)&lq[b][SWZ(ns + lcol, kk)];
            short8 bq1 = *(const short8*)&lq[b][SWZ(ns + 16 + lcol, kk)];
            short8 ah0 = *(const short8*)&lxh[b][SWZ(mt + lcol, kk)];
            short8 al0 = *(const short8*)&lxl[b][SWZ(mt + lcol, kk)];
            short8 ah1 = *(const short8*)&lxh[b][SWZ(mt + 16 + lcol, kk)];
            short8 al1 = *(const short8*)&lxl[b][SWZ(mt + 16 + lcol, kk)];
            p00 = __builtin_amdgcn_mfma_f32_16x16x32_bf16(ah0, bq0, p00, 0, 0, 0);
            p00 = __builtin_amdgcn_mfma_f32_16x16x32_bf16(al0, bq0, p00, 0, 0, 0);
            p01 = __builtin_amdgcn_mfma_f32_16x16x32_bf16(ah0, bq1, p01, 0, 0, 0);
            p01 = __builtin_amdgcn_mfma_f32_16x16x32_bf16(al0, bq1, p01, 0, 0, 0);
            p10 = __builtin_amdgcn_mfma_f32_16x16x32_bf16(ah1, bq0, p10, 0, 0, 0);
            p10 = __builtin_amdgcn_mfma_f32_16x16x32_bf16(al1, bq0, p10, 0, 0, 0);
            p11 = __builtin_amdgcn_mfma_f32_16x16x32_bf16(ah1, bq1, p11, 0, 0, 0);
            p11 = __builtin_amdgcn_mfma_f32_16x16x32_bf16(al1, bq1, p11, 0, 0, 0);
            ps0 = __builtin_amdgcn_mfma_f32_16x16x32_bf16(ah0, ones, ps0, 0, 0, 0);
            ps0 = __builtin_amdgcn_mfma_f32_16x16x32_bf16(al0, ones, ps0, 0, 0, 0);
            ps1 = __builtin_amdgcn_mfma_f32_16x16x32_bf16(ah1, ones, ps1, 0, 0, 0);
            ps1 = __builtin_amdgcn_mfma_f32_16x16x32_bf16(al1, ones, ps1, 0, 0, 0);
        }
        {   // group fold (LDS tables + in-register xsum)
            const float s0 = ls[g][ns + lcol],      z0 = lz[g][ns + lcol];
            const float s1 = ls[g][ns + 16 + lcol], z1 = lz[g][ns + 16 + lcol];
#pragma unroll
            for (int r = 0; r < 4; ++r) {
                acc00[r] += s0 * (p00[r] - z0 * ps0[r]);
                acc01[r] += s1 * (p01[r] - z1 * ps0[r]);
                acc10[r] += s0 * (p10[r] - z0 * ps1[r]);
                acc11[r] += s1 * (p11[r] - z1 * ps1[r]);
            }
        }

        if (g + 1 < NG2) {
            WRITEX(b ^ 1);                        // waits x(g+1); q(g+1) stays
            if (g + 2 < NG2) {
                LOADX(g0 + g + 2);                // outstanding during q drain
                __builtin_amdgcn_sched_barrier(0);
            }
            WRITEQ(b ^ 1);                        // waits q(g+1); x(g+2) in flight
            if (g + 2 < NG2) {
                LOADQ(g0 + g + 2);                // refill queue immediately
                __builtin_amdgcn_sched_barrier(0);
            }
            asm volatile("s_waitcnt lgkmcnt(0)" ::: "memory");
            __builtin_amdgcn_s_barrier();         // RAW: vmcnt survives
        }
    }

    const size_t ob = (size_t)kh * Mdim * Ndim;
#pragma unroll
    for (int r = 0; r < 4; ++r) {
        pout[ob + (size_t)(mt + lhi * 4 + r) * Ndim + c0] = acc00[r];
        pout[ob + (size_t)(mt + lhi * 4 + r) * Ndim + c1] = acc01[r];
        pout[ob + (size_t)(mt + 16 + lhi * 4 + r) * Ndim + c0] = acc10[r];
        pout[ob + (size_t)(mt + 16 + lhi * 4 + r) * Ndim + c1] = acc11[r];
    }
}

// out = sum of KSPLIT partials + bias
__global__ void reduce_kernel(const float* __restrict__ pout,
                              const float* __restrict__ bias,
                              float* __restrict__ out) {
    const size_t e = ((size_t)blockIdx.x * 256 + threadIdx.x) * 4;
    const int n = (int)(e & (Ndim - 1));
    f32x4 a = *(const f32x4*)(bias + n);
#pragma unroll
    for (int s = 0; s < KSPLIT; ++s) {
        f32x4 ppart = *(const f32x4*)(pout + (size_t)s * Mdim * Ndim + e);
#pragma unroll
        for (int r = 0; r < 4; ++r) a[r] += ppart[r];
    }
    *(f32x4*)(out + e) = a;
}

extern "C" void kernel_launch(void* const* d_in, const int* in_sizes, int n_in,
                              void* d_out, int out_size, void* d_ws, size_t ws_size,
                              hipStream_t stream) {
    const float* x = (const float*)d_in[0];
    const int* qw = (const int*)d_in[1];
    const float* scales = (const float*)d_in[2];
    const float* zeros = (const float*)d_in[3];
    const float* bias = (const float*)d_in[4];

    float* pout = (float*)d_ws;
    float* out = (float*)d_out;

    qlin_kernel<<<(Ndim / BN) * KSPLIT, 512, 0, stream>>>(x, qw, scales, zeros, pout);
    reduce_kernel<<<(Mdim * Ndim / 4) / 256, 256, 0, stream>>>(pout, bias, out);
}